// Round 6
// baseline (209.918 us; speedup 1.0000x reference)
//
#include <hip/hip_runtime.h>
#include <hip/hip_bf16.h>
#include <stdint.h>

#define B_DIM 8
#define T_DIM 2048
#define H_DIM 512
#define NC 32       // chunks per batch
#define LCH 64      // chunk length
#define NSUB 4      // sub-chunks per chunk
#define LSUB 16     // steps per sub-chunk
#define NSEG (NC * NSUB)   // 128 segments per batch
#define NOCT 8             // octets per batch (16 segments each)
#define BM 128
#define BN 128
#define BK 32

typedef float floatx4 __attribute__((ext_vector_type(4)));
typedef __bf16 bf16x4 __attribute__((ext_vector_type(4)));
typedef __bf16 bf16x8 __attribute__((ext_vector_type(8)));

// Block-local recompute of global min/max of e (64 KB, L2-broadcast; fmin/fmax
// are order-independent so this is bit-identical to a dedicated pass).
// Returns via sst[0]=mn, sst[1]=1/(mx-mn). Requires 512 threads.
__device__ __forceinline__ void block_minmax(const float* __restrict__ e,
                                             float* __restrict__ sst /*LDS[2]*/,
                                             float* __restrict__ smn /*LDS[8]*/,
                                             float* __restrict__ smx /*LDS[8]*/) {
    const int tid = threadIdx.x;
    const float4* e4 = (const float4*)e;
    float mn = 1e30f, mx = -1e30f;
    #pragma unroll
    for (int i = 0; i < 8; ++i) {
        float4 v = e4[tid + i * 512];
        mn = fminf(mn, fminf(fminf(v.x, v.y), fminf(v.z, v.w)));
        mx = fmaxf(mx, fmaxf(fmaxf(v.x, v.y), fmaxf(v.z, v.w)));
    }
    #pragma unroll
    for (int off = 32; off > 0; off >>= 1) {
        mn = fminf(mn, __shfl_down(mn, off, 64));
        mx = fmaxf(mx, __shfl_down(mx, off, 64));
    }
    const int wid = tid >> 6;
    if ((tid & 63) == 0) { smn[wid] = mn; smx[wid] = mx; }
    __syncthreads();
    if (tid == 0) {
        mn = smn[0]; mx = smx[0];
        #pragma unroll
        for (int w = 1; w < 8; ++w) { mn = fminf(mn, smn[w]); mx = fmaxf(mx, smx[w]); }
        sst[0] = mn;
        sst[1] = 1.0f / (mx - mn);
    }
    __syncthreads();
}

// ---------------- K1: per-sub-chunk local scan (zero-init), emit h_bf + per-sub summaries.
__global__ __launch_bounds__(512) void chunk_sum_kernel(
        const float* __restrict__ e, const float* __restrict__ h,
        __hip_bfloat16* __restrict__ h_bf,
        float* __restrict__ Lsub, float* __restrict__ PPsub, float* __restrict__ LDsub) {
    const int b = blockIdx.x, c = blockIdx.y;
    const int tid = threadIdx.x;
    const int hdq = tid & 127, sub = tid >> 7;
    const int hd = hdq * 4;
    const int t0 = c * LCH + sub * LSUB;

    __shared__ float sst[2], smn[8], smx[8];
    __shared__ float se[LCH];   // multiplier a for step j of this chunk
    block_minmax(e, sst, smn, smx);

    if (tid < LCH) {
        int t = c * LCH + tid;
        se[tid] = (t == 0) ? 0.0f : (e[b * T_DIM + t - 1] - sst[0]) * sst[1];
    }
    __syncthreads();

    const float* hp = h + ((size_t)b * T_DIM + t0) * H_DIM + hd;
    __hip_bfloat16* hbp = h_bf + ((size_t)b * T_DIM + t0) * H_DIM + hd;

    floatx4 lv = {0.0f, 0.0f, 0.0f, 0.0f};
    float ldv = 0.0f, pp = 1.0f;
    #pragma unroll 8
    for (int i = 0; i < LSUB; ++i) {
        float a = se[sub * LSUB + i];
        floatx4 hv = *(const floatx4*)(hp + (size_t)i * H_DIM);
        lv = a * lv + hv;
        ldv = fmaf(a, ldv, 1.0f);
        pp *= a;
        bf16x4 o;
        #pragma unroll
        for (int k = 0; k < 4; ++k) o[k] = (__bf16)hv[k];
        *(bf16x4*)(hbp + (size_t)i * H_DIM) = o;
    }
    int seg = (b * NC + c) * NSUB + sub;
    *(floatx4*)(Lsub + (size_t)seg * H_DIM + hd) = lv;
    if (hdq == 0) { PPsub[seg] = pp; LDsub[seg] = ldv; }
}

// ---------------- K2: per-octet ZERO-SEEDED prefixes + octet aggregate, one pass.
__global__ __launch_bounds__(512) void octprefix_kernel(
        const float* __restrict__ Lsub, const float* __restrict__ PPsub,
        const float* __restrict__ LDsub,
        float* __restrict__ Spart, float* __restrict__ Ppre, float* __restrict__ SDpart,
        float* __restrict__ Loct, float* __restrict__ Poct, float* __restrict__ LDoct) {
    const int b = blockIdx.x, o = blockIdx.y, hd = threadIdx.x;
    float sp = 0.0f, sdp = 0.0f, pp = 1.0f;
    #pragma unroll 4
    for (int i = 0; i < 16; ++i) {
        int seg = b * NSEG + o * 16 + i;
        Spart[(size_t)seg * H_DIM + hd] = sp;
        if (hd == 0) { Ppre[seg] = pp; SDpart[seg] = sdp; }
        float pe = PPsub[seg];
        sp  = fmaf(pe, sp,  Lsub[(size_t)seg * H_DIM + hd]);
        sdp = fmaf(pe, sdp, LDsub[seg]);
        pp *= pe;
    }
    int oc = b * NOCT + o;
    Loct[(size_t)oc * H_DIM + hd] = sp;
    if (hd == 0) { Poct[oc] = pp; LDoct[oc] = sdp; }
}

// ---------------- K3: rescan sub-chunk from h_bf. Octet entering state is folded
// IN-KERNEL from Loct/Poct (<=7 steps, L2-resident), then seed = Ppre*Soct + Spart.
__global__ __launch_bounds__(512) void rescan_kernel(
        const float* __restrict__ e, const __hip_bfloat16* __restrict__ h_bf,
        const float* __restrict__ Spart, const float* __restrict__ Ppre,
        const float* __restrict__ SDpart,
        const float* __restrict__ Loct, const float* __restrict__ Poct,
        const float* __restrict__ LDoct,
        __hip_bfloat16* __restrict__ hagg_bf) {
    const int b = blockIdx.x, c = blockIdx.y;
    const int tid = threadIdx.x;
    const int hdq = tid & 127, sub = tid >> 7;
    const int hd = hdq * 4;
    const int t0 = c * LCH + sub * LSUB;

    __shared__ float sst[2], smn[8], smx[8];
    __shared__ float se[LCH];
    block_minmax(e, sst, smn, smx);

    if (tid < LCH) {
        int t = c * LCH + tid;
        se[tid] = (t == 0) ? 0.0f : (e[b * T_DIM + t - 1] - sst[0]) * sst[1];
    }
    __syncthreads();

    const int seg = (b * NC + c) * NSUB + sub;
    const int oct = c >> 2;
    const __hip_bfloat16* hbp = h_bf + ((size_t)b * T_DIM + t0) * H_DIM + hd;
    __hip_bfloat16* hop = hagg_bf + ((size_t)b * T_DIM + t0) * H_DIM + hd;

    // Fold octets 0..oct-1 (same order/fma as the old octfold kernel -> bit-identical).
    floatx4 soct = {0.0f, 0.0f, 0.0f, 0.0f};
    float sdoct = 0.0f;
    for (int o = 0; o < oct; ++o) {
        int oc = b * NOCT + o;
        float P = Poct[oc];
        floatx4 lo = *(const floatx4*)(Loct + (size_t)oc * H_DIM + hd);
        soct = P * soct + lo;
        sdoct = fmaf(P, sdoct, LDoct[oc]);
    }

    const float pq = Ppre[seg];
    floatx4 spart = *(const floatx4*)(Spart + (size_t)seg * H_DIM + hd);
    floatx4 s = pq * soct + spart;
    float sd = fmaf(pq, sdoct, SDpart[seg]);

    #pragma unroll 8
    for (int i = 0; i < LSUB; ++i) {
        float a = se[sub * LSUB + i];
        bf16x4 hb = *(const bf16x4*)(hbp + (size_t)i * H_DIM);
        floatx4 hv;
        #pragma unroll
        for (int k = 0; k < 4; ++k) hv[k] = (float)hb[k];
        s = a * s + hv;
        sd = fmaf(a, sd, 1.0f);
        float inv = 1.0f / sd;
        bf16x4 o;
        #pragma unroll
        for (int k = 0; k < 4; ++k) o[k] = (__bf16)(s[k] * inv);
        *(bf16x4*)(hop + (size_t)i * H_DIM) = o;
    }
}

// ---------------- K4: batched NT-GEMM, C[b,t,s] = (1/sqrt(H)) * A[b,t,:] . B[b,s,:]
// 128x128 tile, 256 threads (4 waves), BK=32 DOUBLE-BUFFERED in the same 32 KiB LDS
// (occupancy preserved at 3-4 blocks/CU) with COUNTED vmcnt(4): tile t+1's 4 loads
// stay in flight across the barrier; vmcnt never drains to 0 in steady state (T4).
// Granule perm p(row)=(row>>1)&3 keeps both LDS read phases 2-way (free).
// K-accumulation order identical to the BK=64 version -> bit-identical output.
__device__ __forceinline__ void async16(const void* g, void* l) {
    __builtin_amdgcn_global_load_lds(
        (__attribute__((address_space(1))) void*)g,
        (__attribute__((address_space(3))) void*)l,
        16, 0, 0);
}

__global__ __launch_bounds__(256) void gemm_kernel(
        const __hip_bfloat16* __restrict__ Abf,   // h_bf   [B][T][H]
        const __hip_bfloat16* __restrict__ Bbf,   // hagg_bf[B][T][H]
        float* __restrict__ C) {                  // [B][T][T]
    __shared__ __align__(16) char lds[32768];
    char* AsB = lds;            // 2 bufs x 8 KB
    char* BsB = lds + 16384;    // 2 bufs x 8 KB

    // Batch-per-XCD pin (id%8 == batch) for L2 locality of the 4 MB A+B set.
    const int id = blockIdx.x + (blockIdx.y << 4) + (blockIdx.z << 8);
    const int b  = id & 7;
    const int tt = id >> 3;
    const int tm = (tt & 15) * BM;
    const int sn = (tt >> 4) * BN;

    const int tid = threadIdx.x;
    const int lane = tid & 63;
    const int wave = tid >> 6;
    const int wm = (wave >> 1) * 64;
    const int wn = (wave & 1) * 64;
    const int l16 = lane & 15;
    const int quad = lane >> 4;

    // Staging: thread tid covers rows (tid>>2) and (tid>>2)+64; slot tid&3 of
    // row r holds global k-granule (tid&3) ^ ((r>>1)&3)  (XOR perm applied on
    // the GLOBAL source; LDS dest stays linear as global_load_lds requires;
    // (r>>1)&3 is invariant under r+=64 so one precomputed sg serves both rounds).
    const int srow = tid >> 2;                       // 0..63
    const int sg = (tid & 3) ^ ((srow >> 1) & 3);
    const __hip_bfloat16* Ag = Abf + ((size_t)b * T_DIM + tm + srow) * H_DIM + sg * 8;
    const __hip_bfloat16* Bg = Bbf + ((size_t)b * T_DIM + sn + srow) * H_DIM + sg * 8;

    floatx4 zero = {0.0f, 0.0f, 0.0f, 0.0f};
    floatx4 acc[4][4];
    #pragma unroll
    for (int i = 0; i < 4; ++i)
        #pragma unroll
        for (int j = 0; j < 4; ++j) acc[i][j] = zero;

    // Stage K-tile kt (128 rows x 32 k) into buffer buf: 4 loads/thread.
    #define STAGE(kt, buf) do {                                                   \
        const int kk_ = (kt) * BK;                                                \
        async16(Ag + kk_,                        AsB + (buf) * 8192 + tid * 16);  \
        async16(Ag + (size_t)64 * H_DIM + kk_,   AsB + (buf) * 8192 + 4096 + tid * 16); \
        async16(Bg + kk_,                        BsB + (buf) * 8192 + tid * 16);  \
        async16(Bg + (size_t)64 * H_DIM + kk_,   BsB + (buf) * 8192 + 4096 + tid * 16); \
    } while (0)

    STAGE(0, 0);
    const int NT = H_DIM / BK;   // 16 K-tiles
    for (int t = 0; t < NT; ++t) {
        const int cur = t & 1;
        if (t < NT - 1) {
            STAGE(t + 1, cur ^ 1);
            // Outstanding <= 8; wait to <=4: in-order retirement means tile t's
            // 4 oldest are done, tile t+1's 4 stay in flight across the barrier.
            asm volatile("s_waitcnt vmcnt(4)" ::: "memory");
        } else {
            asm volatile("s_waitcnt vmcnt(0)" ::: "memory");
        }
        __builtin_amdgcn_s_barrier();   // raw: does NOT drain vmcnt

        const char* Ab = AsB + cur * 8192;
        const char* Bb = BsB + cur * 8192;
        bf16x8 af[4], bv[4];
        #pragma unroll
        for (int j = 0; j < 4; ++j) {
            int rb = wn + j * 16 + l16;
            int gb = quad ^ ((rb >> 1) & 3);
            bv[j] = *reinterpret_cast<const bf16x8*>(Bb + rb * 64 + gb * 16);
        }
        #pragma unroll
        for (int i = 0; i < 4; ++i) {
            int ra = wm + i * 16 + l16;
            int ga = quad ^ ((ra >> 1) & 3);
            af[i] = *reinterpret_cast<const bf16x8*>(Ab + ra * 64 + ga * 16);
        }
        __builtin_amdgcn_s_setprio(1);
        #pragma unroll
        for (int i = 0; i < 4; ++i)
            #pragma unroll
            for (int j = 0; j < 4; ++j)
                acc[i][j] = __builtin_amdgcn_mfma_f32_16x16x32_bf16(
                    bv[j], af[i], acc[i][j], 0, 0, 0);
        __builtin_amdgcn_s_setprio(0);
        // All this wave's ds_reads retired before signaling; the barrier then
        // makes it legal for the next iteration's STAGE to overwrite buf[cur].
        asm volatile("s_waitcnt lgkmcnt(0)" ::: "memory");
        __builtin_amdgcn_s_barrier();
    }
    #undef STAGE

    const float scale = 0.04419417382415922f;  // 1/sqrt(512)
    float* Cp = C + (size_t)b * T_DIM * T_DIM;
    // Swapped-operand D mapping: col(lane&15) -> t (A-row), row(quad*4+r) -> s (B-row).
    #pragma unroll
    for (int i = 0; i < 4; ++i) {
        int row = tm + wm + i * 16 + l16;              // t
        float* crow = Cp + (size_t)row * T_DIM;
        #pragma unroll
        for (int j = 0; j < 4; ++j) {
            int col = sn + wn + j * 16 + quad * 4;     // s base (16B aligned)
            floatx4 v;
            #pragma unroll
            for (int r = 0; r < 4; ++r) v[r] = acc[i][j][r] * scale;
            *(floatx4*)(crow + col) = v;
        }
    }
}

extern "C" void kernel_launch(void* const* d_in, const int* in_sizes, int n_in,
                              void* d_out, int out_size, void* d_ws, size_t ws_size,
                              hipStream_t stream) {
    const float* e = (const float*)d_in[0];
    const float* h = (const float*)d_in[1];
    // d_in[2] (ilens) is unused by the reference output.
    float* out = (float*)d_out;

    char* ws = (char*)d_ws;
    __hip_bfloat16* h_bf    = (__hip_bfloat16*)(ws + 4096);                  // 16 MB
    __hip_bfloat16* hagg_bf = (__hip_bfloat16*)(ws + 4096 + (16u << 20));    // 16 MB
    char* p = ws + 4096 + (32u << 20);
    float* Lsub  = (float*)p;   p += (size_t)B_DIM * NSEG * H_DIM * 4;       // 2 MB
    float* Spart = (float*)p;   p += (size_t)B_DIM * NSEG * H_DIM * 4;       // 2 MB
    float* PPsub = (float*)p;   p += B_DIM * NSEG * 4;                       // 4 KB
    float* LDsub = (float*)p;   p += B_DIM * NSEG * 4;                       // 4 KB
    float* Ppre  = (float*)p;   p += B_DIM * NSEG * 4;                       // 4 KB
    float* SDpart= (float*)p;   p += B_DIM * NSEG * 4;                       // 4 KB
    float* Loct  = (float*)p;   p += (size_t)B_DIM * NOCT * H_DIM * 4;       // 128 KB
    float* Poct  = (float*)p;   p += B_DIM * NOCT * 4;                       // 256 B
    float* LDoct = (float*)p;

    chunk_sum_kernel<<<dim3(B_DIM, NC), 512, 0, stream>>>(e, h, h_bf, Lsub, PPsub, LDsub);
    octprefix_kernel<<<dim3(B_DIM, NOCT), 512, 0, stream>>>(Lsub, PPsub, LDsub,
                                                            Spart, Ppre, SDpart,
                                                            Loct, Poct, LDoct);
    rescan_kernel<<<dim3(B_DIM, NC), 512, 0, stream>>>(e, h_bf, Spart, Ppre, SDpart,
                                                       Loct, Poct, LDoct, hagg_bf);
    gemm_kernel<<<dim3(T_DIM / BM, T_DIM / BN, B_DIM), 256, 0, stream>>>(h_bf, hagg_bf, out);
}